// Round 14
// baseline (97.323 us; speedup 1.0000x reference)
//
#include <hip/hip_runtime.h>
#include <math.h>
#include <utility>

#define NPTS 262144
#define K 32
#define D 16
#define R 160            // 136 triangle + 16 linear + 8 pad -> 10 MFMA K-steps
#define NSTEPS 10
#define NBLK 1024        // 4 waves/block, 2 tiles/wave -> 8192 tiles
#define LROW 352         // 20 data granules + 2 pad granules per theta row
#define LHALF 11264      // 32 rows * 352 B ; thetaL image offset
#define IMG_BYTES 22528  // 2 * LHALF
#define REPS 10          // INSTRUMENTATION: full-body rep loop -> top-5 visible

typedef _Float16 f16x2 __attribute__((ext_vector_type(2)));
typedef _Float16 f16x8 __attribute__((ext_vector_type(8)));
typedef __attribute__((ext_vector_type(16))) float f32x16;
typedef __attribute__((ext_vector_type(4))) int int4v;

// ---- compile-time dual-cell table (round-12 pairing) -------------------
struct PTab {
  short dty[40], cu0[40], cv0[40], cu1[40], cv1[40];
  short pd[160], pf[160];
  constexpr PTab() : dty{}, cu0{}, cv0{}, cu1{}, cv1{}, pd{}, pf{} {
    int n = 0;
    for (int j = 0; j < 8; ++j)                     // 28 ROW duals
      for (int i = 0; i < j; ++i) {
        dty[n]=0; cu0[n]=(short)(2*i); cv0[n]=(short)j;
        cu1[n]=(short)(2*i+1); cv1[n]=(short)j; ++n;
      }
    for (int t = 0; t < 4; ++t) {                   // 4 ROWX duals
      dty[n]=1; cu0[n]=(short)(4*t); cv0[n]=(short)(2*t);
      cu1[n]=(short)(4*t+2); cv1[n]=(short)(2*t+1); ++n;
    }
    for (int t = 0; t < 2; ++t) {                   // 2 DIAG duals
      dty[n]=2; cu0[n]=(short)(2*t); cu1[n]=(short)(2*t+1);
      cv0[n]=0; cv1[n]=0; ++n;
    }
    for (int t = 0; t < 4; ++t) {                   // 4 LIN duals
      dty[n]=3; cu0[n]=(short)(2*t); cu1[n]=(short)(2*t+1);
      cv0[n]=0; cv1[n]=0; ++n;
    }
    for (int t = 0; t < 2; ++t) {                   // 2 PAD duals
      dty[n]=4; cu0[n]=0; cu1[n]=0; cv0[n]=0; cv1[n]=0; ++n;
    }
    for (int c = 0; c < 40; ++c) {
      int S = c / 4, a = c % 4;
      for (int kh = 0; kh < 2; ++kh)
        for (int e = 0; e < 2; ++e) {
          int q = S*16 + kh*8 + a*2 + e;
          int ty = dty[c];
          int u = kh ? cu1[c] : cu0[c];
          int v = kh ? cv1[c] : cv0[c];
          if (ty == 0 || ty == 1) { pd[q] = (short)u; pf[q] = (short)(2*v + e); }
          else if (ty == 2) { int s = u; pd[q] = pf[q] = (short)(4*s + 1 + 2*e); }
          else if (ty == 3) { pd[q] = 16; pf[q] = (short)(2*u + e); }
          else { pd[q] = 17; pf[q] = 0; }
        }
    }
  }
};
static constexpr PTab TAB{};

// ---------------- prep kernel: one block per component k ----------------
// Transcendentals now parallel: LDL loop stores pivots; afterwards tid<16
// does one logf each, tid in [32,64) one expf each; tid0 only sums.
__global__ __launch_bounds__(256) void gm_prep_kernel(
    const float* __restrict__ m_w,
    const float* __restrict__ l_fac,
    const float* __restrict__ p_logits,
    char* __restrict__ thimg,
    float* __restrict__ lc_out)
{
  const int k = blockIdx.x;
  const int tid = threadIdx.x;
  const int r = tid >> 4, c = tid & 15;
  __shared__ float A[D][D];
  __shared__ float L[D][D];
  __shared__ float S[2][D][D];
  __shared__ float Gd[D];
  __shared__ float piv[D];
  __shared__ float ld[D];
  __shared__ float sm[K];
  __shared__ float sme[K];
  __shared__ float smax;
  const float LOG2E = 1.4426950408889634f;

  A[r][c] = l_fac[k * D * D + r * D + c];
  if (tid < K) sm[tid] = p_logits[tid];
  __syncthreads();

  {
    float s = 0.f;
    #pragma unroll
    for (int e = 0; e < D; ++e) s += A[r][e] * A[c][e];
    s *= (1.0f / D);
    L[r][c] = s;
    S[0][r][c] = s;
  }
  if (tid == 0) {
    float mx = -1e30f;
    for (int i = 0; i < K; ++i) mx = fmaxf(mx, sm[i]);
    smax = mx;
  }
  __syncthreads();

  if (tid < D) {
    float s = 0.f;
    #pragma unroll
    for (int f = 0; f < D; ++f) s += L[tid][f] * m_w[k * D + f];
    Gd[tid] = s;
  }

  int cb = 0;
  for (int j = 0; j < 15; ++j) {
    float pj = S[cb][j][j];
    float a = S[cb][r][j], b = S[cb][c][j], v = S[cb][r][c];
    if (tid == 0) piv[j] = pj;
    if (r > j && c > j) S[cb ^ 1][r][c] = v - a * b / pj;
    cb ^= 1;
    __syncthreads();
  }
  if (tid == 0) piv[15] = S[cb][15][15];
  __syncthreads();

  // parallel transcendentals
  if (tid < D) ld[tid] = logf(piv[tid]);
  else if (tid >= 32 && tid < 32 + K) sme[tid - 32] = expf(sm[tid - 32] - smax);
  __syncthreads();

  if (tid == 0) {
    float z = 0.f;
    for (int i = 0; i < K; ++i) z += sme[i];
    float logp = sm[k] - smax - logf(z);
    float logdet_sqrt = 0.f;
    for (int j = 0; j < D; ++j) logdet_sqrt += ld[j];
    logdet_sqrt *= 0.5f;
    float cc = 0.f;
    for (int d2 = 0; d2 < D; ++d2) cc += m_w[k * D + d2] * Gd[d2];
    float lc = logp - 14.703016531274763f + logdet_sqrt - 0.5f * cc;
    lc_out[k] = LOG2E * lc;
  }
  __syncthreads();

  // theta -> fp16 hi/lo, stored at the swizzled image position
  for (int q = tid; q < R; q += 256) {
    int d = TAB.pd[q], f = TAB.pf[q];
    float th;
    if (d == 17) th = 0.f;
    else if (d == 16) th = LOG2E * Gd[f];
    else th = ((d == f) ? -0.5f : -1.0f) * LOG2E * L[d][f];
    _Float16 h = (_Float16)th;           // RNE
    _Float16 l = (_Float16)(th - (float)h);
    int m = q >> 3, e = q & 7;
    int sg = (k & 7) ^ (k >> 3);
    int phys = (m < 16) ? (m ^ sg) : (16 + ((m - 16) ^ (sg & 3)));
    size_t off = (size_t)k * LROW + (size_t)phys * 16 + (size_t)e * 2;
    *(unsigned short*)(thimg + off)         = __builtin_bit_cast(unsigned short, h);
    *(unsigned short*)(thimg + LHALF + off) = __builtin_bit_cast(unsigned short, l);
  }
}

__device__ __forceinline__ int bcst(f16x2 v) { return __builtin_bit_cast(int, v); }
__device__ __forceinline__ f16x2 fint(int v) { return __builtin_bit_cast(f16x2, v); }
__device__ __forceinline__ f16x2 pkrtz(float a, float b) {
  return __builtin_bit_cast(f16x2, __builtin_amdgcn_cvt_pkrtz(a, b));
}

template<int C>
__device__ __forceinline__ void dualphi(int kh,
    const f16x2 (&xh)[8], const f16x2 (&xl)[8],
    const f16x2 (&sH)[16], const f16x2 (&sL)[16],
    const f16x2 (&dgh)[4], const f16x2 (&dgl)[4],
    int& hh, int& cx)
{
  constexpr int ty = TAB.dty[C];
  constexpr int U0 = TAB.cu0[C], V0 = TAB.cv0[C];
  constexpr int U1 = TAB.cu1[C], V1 = TAB.cv1[C];
  if constexpr (ty == 4) { hh = 0; cx = 0; }
  else if constexpr (ty == 3) {
    hh = kh ? bcst(xh[U1]) : bcst(xh[U0]);
    cx = kh ? bcst(xl[U1]) : bcst(xl[U0]);
  } else if constexpr (ty == 2) {
    f16x2 Dh = fint(kh ? bcst(dgh[U1]) : bcst(dgh[U0]));
    f16x2 Dl = fint(kh ? bcst(dgl[U1]) : bcst(dgl[U0]));
    f16x2 m = Dh * Dl;
    hh = bcst(Dh * Dh);
    cx = bcst(m + m);
  } else {
    f16x2 Uh = fint(kh ? bcst(sH[U1]) : bcst(sH[U0]));
    f16x2 Ul = fint(kh ? bcst(sL[U1]) : bcst(sL[U0]));
    f16x2 Vh, Vl;
    if constexpr (V0 == V1) { Vh = xh[V0]; Vl = xl[V0]; }
    else {
      Vh = fint(kh ? bcst(xh[V1]) : bcst(xh[V0]));
      Vl = fint(kh ? bcst(xl[V1]) : bcst(xl[V0]));
    }
    hh = bcst(Uh * Vh);
    cx = bcst(__builtin_elementwise_fma(Uh, Vl, Ul * Vh));
  }
}

template<int S>
__device__ __forceinline__ void do_step(int kh,
    const f16x2 (&xh)[8], const f16x2 (&xl)[8],
    const f16x2 (&sH)[16], const f16x2 (&sL)[16],
    const f16x2 (&dgh)[4], const f16x2 (&dgl)[4],
    const char* lthp, int base2, int sigh, f32x16& acc)
{
  int va;
  if constexpr (S < 8) va = base2 + ((S ^ sigh) << 5);
  else                 va = base2 + 256 + (((S - 8) ^ (sigh & 1)) << 5);
  int4v thv = *(const int4v*)(lthp + va);
  int4v tlv = *(const int4v*)(lthp + va + LHALF);
  int h0, h1, h2, h3, c0, c1, c2, c3;
  dualphi<S*4+0>(kh, xh, xl, sH, sL, dgh, dgl, h0, c0);
  dualphi<S*4+1>(kh, xh, xl, sH, sL, dgh, dgl, h1, c1);
  dualphi<S*4+2>(kh, xh, xl, sH, sL, dgh, dgl, h2, c2);
  dualphi<S*4+3>(kh, xh, xl, sH, sL, dgh, dgl, h3, c3);
  int4v hh = {h0, h1, h2, h3};
  int4v cx = {c0, c1, c2, c3};
  acc = __builtin_amdgcn_mfma_f32_32x32x16_f16(
      __builtin_bit_cast(f16x8, thv), __builtin_bit_cast(f16x8, hh), acc, 0, 0, 0);
  acc = __builtin_amdgcn_mfma_f32_32x32x16_f16(
      __builtin_bit_cast(f16x8, tlv), __builtin_bit_cast(f16x8, hh), acc, 0, 0, 0);
  acc = __builtin_amdgcn_mfma_f32_32x32x16_f16(
      __builtin_bit_cast(f16x8, thv), __builtin_bit_cast(f16x8, cx), acc, 0, 0, 0);
}

template<int... Ss>
__device__ __forceinline__ void all_steps(std::integer_sequence<int, Ss...>,
    int kh, const f16x2 (&xh)[8], const f16x2 (&xl)[8],
    const f16x2 (&sH)[16], const f16x2 (&sL)[16],
    const f16x2 (&dgh)[4], const f16x2 (&dgl)[4],
    const char* lthp, int base2, int sigh, f32x16& acc)
{
  (do_step<Ss>(kh, xh, xl, sH, sL, dgh, dgl, lthp, base2, sigh, acc), ...);
}

__device__ __forceinline__ void process_tile(
    const float4 (&xv)[4], int t, int lane, int p, int kh,
    const char* lthp, int base2, int sigh, const float (&lcv)[16],
    float* __restrict__ out)
{
  float xs[16];
  xs[0]=xv[0].x; xs[1]=xv[0].y; xs[2]=xv[0].z; xs[3]=xv[0].w;
  xs[4]=xv[1].x; xs[5]=xv[1].y; xs[6]=xv[1].z; xs[7]=xv[1].w;
  xs[8]=xv[2].x; xs[9]=xv[2].y; xs[10]=xv[2].z; xs[11]=xv[2].w;
  xs[12]=xv[3].x; xs[13]=xv[3].y; xs[14]=xv[3].z; xs[15]=xv[3].w;

  f16x2 xh[8], xl[8];
  #pragma unroll
  for (int i = 0; i < 8; ++i) {
    f16x2 h = pkrtz(xs[2*i], xs[2*i+1]);
    xh[i] = h;
    xl[i] = pkrtz(xs[2*i] - (float)h[0], xs[2*i+1] - (float)h[1]);
  }
  f16x2 sH[16], sL[16], dgh[4], dgl[4];
  #pragma unroll
  for (int i = 0; i < 8; ++i) {
    sH[2*i]   = __builtin_shufflevector(xh[i], xh[i], 0, 0);
    sH[2*i+1] = __builtin_shufflevector(xh[i], xh[i], 1, 1);
    sL[2*i]   = __builtin_shufflevector(xl[i], xl[i], 0, 0);
    sL[2*i+1] = __builtin_shufflevector(xl[i], xl[i], 1, 1);
  }
  #pragma unroll
  for (int s = 0; s < 4; ++s) {
    dgh[s] = __builtin_shufflevector(xh[2*s], xh[2*s+1], 1, 3);
    dgl[s] = __builtin_shufflevector(xl[2*s], xl[2*s+1], 1, 3);
  }

  f32x16 acc;
  #pragma unroll
  for (int i = 0; i < 16; ++i) acc[i] = 0.f;

  all_steps(std::make_integer_sequence<int, NSTEPS>{}, kh, xh, xl,
            sH, sL, dgh, dgl, lthp, base2, sigh, acc);

  float e[16];
  #pragma unroll
  for (int i = 0; i < 16; ++i)
    e[i] = __builtin_amdgcn_exp2f(acc[i] + lcv[i]);
  float a0 = (e[0] + e[1]) + (e[2] + e[3]);
  float a1 = (e[4] + e[5]) + (e[6] + e[7]);
  float a2 = (e[8] + e[9]) + (e[10] + e[11]);
  float a3 = (e[12] + e[13]) + (e[14] + e[15]);
  float ss = (a0 + a1) + (a2 + a3);
  ss += __shfl_xor(ss, 32);
  if (lane < 32) out[(size_t)t * 32 + p] = ss;
}

// ---------------- density kernel: FULL-BODY rep loop (instrumented) ----------------
// Each rep = {barrier; staging (opaque index, forced reload); barrier;
// phi-split+compute both tiles; stores}. dur/REPS = true per-iteration cost
// incl. staging+barriers; only the one-time x-load is amortized (~1us).
__global__ __launch_bounds__(256) void gm_mfma_kernel(
    const float* __restrict__ x,
    const char*  __restrict__ thimg,
    const float* __restrict__ lc,
    float* __restrict__ out)
{
  __shared__ __align__(16) char lth[IMG_BYTES];
  const int tid = threadIdx.x;
  const int lane = tid & 63;
  const int p = lane & 31;
  const int kh = lane >> 5;
  const int t0 = (blockIdx.x * 4 + (tid >> 6)) * 2;

  // one-time x loads for both tiles
  const float4* xp0 = (const float4*)(x + ((size_t)t0 * 32 + p) * D);
  const float4* xp1 = (const float4*)(x + ((size_t)(t0 + 1) * 32 + p) * D);
  float4 xva[4], xvb[4];
  #pragma unroll
  for (int i = 0; i < 4; ++i) { xva[i] = xp0[i]; xvb[i] = xp1[i]; }

  float lcv[16];
  #pragma unroll
  for (int i = 0; i < 16; ++i)
    lcv[i] = lc[(i & 3) + 8 * (i >> 2) + 4 * kh];

  const int sig = (p & 7) ^ (p >> 3);
  const int base2 = p * LROW + ((kh ^ (sig & 1)) << 4);
  const int sigh = sig >> 1;

  #pragma unroll 1
  for (int rep = 0; rep < REPS; ++rep) {
    __syncthreads();   // LDS safe to overwrite (prev rep's reads done)

    // staging with opaque start index -> loads can't be hoisted across reps
    int i0 = tid;
    asm volatile("" : "+v"(i0));
    for (int i = i0; i < IMG_BYTES / 16; i += 256) {
      int4v v = *(const int4v*)(thimg + i * 16);
      *(int4v*)(lth + i * 16) = v;
    }
    __syncthreads();

    // opaque x registers -> phi split/build re-done per rep
    float4 xa[4], xb[4];
    #pragma unroll
    for (int i = 0; i < 4; ++i) {
      xa[i] = xva[i]; xb[i] = xvb[i];
      asm volatile("" : "+v"(xa[i].x), "+v"(xa[i].y), "+v"(xa[i].z), "+v"(xa[i].w));
      asm volatile("" : "+v"(xb[i].x), "+v"(xb[i].y), "+v"(xb[i].z), "+v"(xb[i].w));
    }

    process_tile(xa, t0,     lane, p, kh, lth, base2, sigh, lcv, out);
    process_tile(xb, t0 + 1, lane, p, kh, lth, base2, sigh, lcv, out);
  }
}

extern "C" void kernel_launch(void* const* d_in, const int* in_sizes, int n_in,
                              void* d_out, int out_size, void* d_ws, size_t ws_size,
                              hipStream_t stream) {
  const float* x        = (const float*)d_in[0];
  const float* m_w      = (const float*)d_in[1];
  const float* l_fac    = (const float*)d_in[2];
  const float* p_logits = (const float*)d_in[3];
  float* out = (float*)d_out;

  char* ws = (char*)d_ws;
  char*  thimg = ws;
  float* lcbuf = (float*)(ws + IMG_BYTES);

  gm_prep_kernel<<<K, 256, 0, stream>>>(m_w, l_fac, p_logits, thimg, lcbuf);
  gm_mfma_kernel<<<NBLK, 256, 0, stream>>>(x, thimg, lcbuf, out);
}

// Round 15
// 22.110 us; speedup vs baseline: 4.4018x; 4.4018x over previous
//
#include <hip/hip_runtime.h>
#include <math.h>
#include <utility>

#define NPTS 262144
#define K 32
#define D 16
#define R 160            // 136 triangle + 16 linear + 8 pad -> 10 MFMA K-steps
#define NSTEPS 10
#define NBLK 2048        // 4 waves/block, 1 tile/wave -> 8192 tiles
#define LROW 352         // 20 data granules + 2 pad granules per theta row
#define LHALF 11264      // 32 rows * 352 B ; thetaL image offset
#define IMG_BYTES 22528  // 2 * LHALF
#define LCSLOT 148       // pad slot carrying lc (hi/lo); phi there == 1.0

typedef _Float16 f16x2 __attribute__((ext_vector_type(2)));
typedef _Float16 f16x8 __attribute__((ext_vector_type(8)));
typedef __attribute__((ext_vector_type(16))) float f32x16;
typedef __attribute__((ext_vector_type(4))) int int4v;

// ---- compile-time dual-cell table (round-12 pairing) -------------------
// ROW duals: u0=2i (kh0) / u1=2i+1 (kh1) -> strict even/odd pattern, so a
// per-tile pre-selected splat array su[i] replaces per-dual selects.
struct PTab {
  short dty[40], cu0[40], cv0[40], cu1[40], cv1[40];
  short pd[160], pf[160];
  constexpr PTab() : dty{}, cu0{}, cv0{}, cu1{}, cv1{}, pd{}, pf{} {
    int n = 0;
    for (int j = 0; j < 8; ++j)                     // 28 ROW duals
      for (int i = 0; i < j; ++i) {
        dty[n]=0; cu0[n]=(short)(2*i); cv0[n]=(short)j;
        cu1[n]=(short)(2*i+1); cv1[n]=(short)j; ++n;
      }
    for (int t = 0; t < 4; ++t) {                   // 4 ROWX duals
      dty[n]=1; cu0[n]=(short)(4*t); cv0[n]=(short)(2*t);
      cu1[n]=(short)(4*t+2); cv1[n]=(short)(2*t+1); ++n;
    }
    for (int t = 0; t < 2; ++t) {                   // 2 DIAG duals
      dty[n]=2; cu0[n]=(short)(2*t); cu1[n]=(short)(2*t+1);
      cv0[n]=0; cv1[n]=0; ++n;
    }
    for (int t = 0; t < 4; ++t) {                   // 4 LIN duals
      dty[n]=3; cu0[n]=(short)(2*t); cu1[n]=(short)(2*t+1);
      cv0[n]=0; cv1[n]=0; ++n;
    }
    for (int t = 0; t < 2; ++t) {                   // 2 PAD duals (cells 38,39)
      dty[n]=4; cu0[n]=0; cu1[n]=0; cv0[n]=0; cv1[n]=0; ++n;
    }
    for (int c = 0; c < 40; ++c) {
      int S = c / 4, a = c % 4;
      for (int kh = 0; kh < 2; ++kh)
        for (int e = 0; e < 2; ++e) {
          int q = S*16 + kh*8 + a*2 + e;
          int ty = dty[c];
          int u = kh ? cu1[c] : cu0[c];
          int v = kh ? cv1[c] : cv0[c];
          if (ty == 0 || ty == 1) { pd[q] = (short)u; pf[q] = (short)(2*v + e); }
          else if (ty == 2) { int s = u; pd[q] = pf[q] = (short)(4*s + 1 + 2*e); }
          else if (ty == 3) { pd[q] = 16; pf[q] = (short)(2*u + e); }
          else { pd[q] = 17; pf[q] = 0; }
        }
    }
  }
};
static constexpr PTab TAB{};

// ---------------- prep kernel: one block per component k ----------------
// Writes theta PRE-SWIZZLED into the ws image (fp16 hi/lo split). lc is
// embedded at pad slot LCSLOT (hi image = hi(lc), lo image = lo(lc)); the
// density kernel's phi there is the constant 1.0 so MFMA adds lc for free.
__global__ __launch_bounds__(256) void gm_prep_kernel(
    const float* __restrict__ m_w,
    const float* __restrict__ l_fac,
    const float* __restrict__ p_logits,
    char* __restrict__ thimg)
{
  const int k = blockIdx.x;
  const int tid = threadIdx.x;
  const int r = tid >> 4, c = tid & 15;
  __shared__ float A[D][D];
  __shared__ float L[D][D];
  __shared__ float S[2][D][D];
  __shared__ float Gd[D];
  __shared__ float piv[D];
  __shared__ float ld[D];
  __shared__ float sm[K];
  __shared__ float sme[K];
  __shared__ float smax;
  __shared__ float lc_sh;
  const float LOG2E = 1.4426950408889634f;

  A[r][c] = l_fac[k * D * D + r * D + c];
  if (tid < K) sm[tid] = p_logits[tid];
  __syncthreads();

  {
    float s = 0.f;
    #pragma unroll
    for (int e = 0; e < D; ++e) s += A[r][e] * A[c][e];
    s *= (1.0f / D);
    L[r][c] = s;
    S[0][r][c] = s;
  }
  if (tid == 0) {
    float mx = -1e30f;
    for (int i = 0; i < K; ++i) mx = fmaxf(mx, sm[i]);
    smax = mx;
  }
  __syncthreads();

  if (tid < D) {
    float s = 0.f;
    #pragma unroll
    for (int f = 0; f < D; ++f) s += L[tid][f] * m_w[k * D + f];
    Gd[tid] = s;
  }

  int cb = 0;
  for (int j = 0; j < 15; ++j) {
    float pj = S[cb][j][j];
    float a = S[cb][r][j], b = S[cb][c][j], v = S[cb][r][c];
    if (tid == 0) piv[j] = pj;
    if (r > j && c > j) S[cb ^ 1][r][c] = v - a * b / pj;
    cb ^= 1;
    __syncthreads();
  }
  if (tid == 0) piv[15] = S[cb][15][15];
  __syncthreads();

  // parallel transcendentals
  if (tid < D) ld[tid] = logf(piv[tid]);
  else if (tid >= 32 && tid < 32 + K) sme[tid - 32] = expf(sm[tid - 32] - smax);
  __syncthreads();

  if (tid == 0) {
    float z = 0.f;
    for (int i = 0; i < K; ++i) z += sme[i];
    float logp = sm[k] - smax - logf(z);
    float logdet_sqrt = 0.f;
    for (int j = 0; j < D; ++j) logdet_sqrt += ld[j];
    logdet_sqrt *= 0.5f;
    float cc = 0.f;
    for (int d2 = 0; d2 < D; ++d2) cc += m_w[k * D + d2] * Gd[d2];
    float lc = logp - 14.703016531274763f + logdet_sqrt - 0.5f * cc;
    lc_sh = LOG2E * lc;
  }
  __syncthreads();

  // theta -> fp16 hi/lo at swizzled image positions; LCSLOT carries lc
  for (int q = tid; q < R; q += 256) {
    int d = TAB.pd[q], f = TAB.pf[q];
    float th;
    if (q == LCSLOT) th = lc_sh;
    else if (d == 17) th = 0.f;
    else if (d == 16) th = LOG2E * Gd[f];
    else th = ((d == f) ? -0.5f : -1.0f) * LOG2E * L[d][f];
    _Float16 h = (_Float16)th;           // RNE
    _Float16 l = (_Float16)(th - (float)h);
    int m = q >> 3, e = q & 7;
    int sg = (k & 7) ^ (k >> 3);
    int phys = (m < 16) ? (m ^ sg) : (16 + ((m - 16) ^ (sg & 3)));
    size_t off = (size_t)k * LROW + (size_t)phys * 16 + (size_t)e * 2;
    *(unsigned short*)(thimg + off)         = __builtin_bit_cast(unsigned short, h);
    *(unsigned short*)(thimg + LHALF + off) = __builtin_bit_cast(unsigned short, l);
  }
}

__device__ __forceinline__ int bcst(f16x2 v) { return __builtin_bit_cast(int, v); }
__device__ __forceinline__ f16x2 fint(int v) { return __builtin_bit_cast(f16x2, v); }
__device__ __forceinline__ f16x2 pkrtz(float a, float b) {
  return __builtin_bit_cast(f16x2, __builtin_amdgcn_cvt_pkrtz(a, b));
}

// build one dword of (phi_hh, phi_cross) for dual C
template<int C>
__device__ __forceinline__ void dualphi(int kh,
    const f16x2 (&xh)[8], const f16x2 (&xl)[8],
    const f16x2 (&su_h)[8], const f16x2 (&su_l)[8],
    const f16x2 (&dgh)[4], const f16x2 (&dgl)[4],
    int& hh, int& cx)
{
  constexpr int ty = TAB.dty[C];
  constexpr int U0 = TAB.cu0[C], V0 = TAB.cv0[C];
  constexpr int U1 = TAB.cu1[C], V1 = TAB.cv1[C];
  if constexpr (ty == 4) {
    if constexpr (C == 38) { hh = 0x3C003C00; cx = 0; }  // phi = 1.0: lc slot
    else { hh = 0; cx = 0; }
  } else if constexpr (ty == 3) {                 // linear: phi = x
    hh = kh ? bcst(xh[U1]) : bcst(xh[U0]);
    cx = kh ? bcst(xl[U1]) : bcst(xl[U0]);
  } else if constexpr (ty == 2) {                 // odd diagonals: x_d^2
    f16x2 Dh = fint(kh ? bcst(dgh[U1]) : bcst(dgh[U0]));
    f16x2 Dl = fint(kh ? bcst(dgl[U1]) : bcst(dgl[U0]));
    f16x2 m = Dh * Dl;
    hh = bcst(Dh * Dh);
    cx = bcst(m + m);
  } else if constexpr (ty == 1) {                 // ROWX: even-diag leftovers
    constexpr int T = U0 >> 2;
    f16x2 uh = fint(kh ? bcst(xh[2*T+1]) : bcst(xh[2*T]));
    f16x2 ul = fint(kh ? bcst(xl[2*T+1]) : bcst(xl[2*T]));
    f16x2 Uh = __builtin_shufflevector(uh, uh, 0, 0);
    f16x2 Ul = __builtin_shufflevector(ul, ul, 0, 0);
    f16x2 Vh = fint(kh ? bcst(xh[V1]) : bcst(xh[V0]));
    f16x2 Vl = fint(kh ? bcst(xl[V1]) : bcst(xl[V0]));
    hh = bcst(Uh * Vh);
    cx = bcst(__builtin_elementwise_fma(Uh, Vl, Ul * Vh));
  } else {                                        // ROW: pre-selected splat
    constexpr int I = U0 >> 1;                    // u0=2I, u1=2I+1 by ctor
    f16x2 Uh = su_h[I], Ul = su_l[I];
    f16x2 Vh = xh[V0], Vl = xl[V0];               // V0==V1 for ROW
    hh = bcst(Uh * Vh);
    cx = bcst(__builtin_elementwise_fma(Uh, Vl, Ul * Vh));
  }
}

template<int S>
__device__ __forceinline__ void do_step(int kh,
    const f16x2 (&xh)[8], const f16x2 (&xl)[8],
    const f16x2 (&su_h)[8], const f16x2 (&su_l)[8],
    const f16x2 (&dgh)[4], const f16x2 (&dgl)[4],
    const char* gth, int base2, int sigh, f32x16& acc)
{
  int va;
  if constexpr (S < 8) va = base2 + ((S ^ sigh) << 5);
  else                 va = base2 + 256 + (((S - 8) ^ (sigh & 1)) << 5);
  int4v thv = *(const int4v*)(gth + va);          // global, L1-resident
  int4v tlv = *(const int4v*)(gth + va + LHALF);
  int h0, h1, h2, h3, c0, c1, c2, c3;
  dualphi<S*4+0>(kh, xh, xl, su_h, su_l, dgh, dgl, h0, c0);
  dualphi<S*4+1>(kh, xh, xl, su_h, su_l, dgh, dgl, h1, c1);
  dualphi<S*4+2>(kh, xh, xl, su_h, su_l, dgh, dgl, h2, c2);
  dualphi<S*4+3>(kh, xh, xl, su_h, su_l, dgh, dgl, h3, c3);
  int4v hh = {h0, h1, h2, h3};
  int4v cx = {c0, c1, c2, c3};
  acc = __builtin_amdgcn_mfma_f32_32x32x16_f16(
      __builtin_bit_cast(f16x8, thv), __builtin_bit_cast(f16x8, hh), acc, 0, 0, 0);
  acc = __builtin_amdgcn_mfma_f32_32x32x16_f16(
      __builtin_bit_cast(f16x8, tlv), __builtin_bit_cast(f16x8, hh), acc, 0, 0, 0);
  acc = __builtin_amdgcn_mfma_f32_32x32x16_f16(
      __builtin_bit_cast(f16x8, thv), __builtin_bit_cast(f16x8, cx), acc, 0, 0, 0);
}

template<int... Ss>
__device__ __forceinline__ void all_steps(std::integer_sequence<int, Ss...>,
    int kh, const f16x2 (&xh)[8], const f16x2 (&xl)[8],
    const f16x2 (&su_h)[8], const f16x2 (&su_l)[8],
    const f16x2 (&dgh)[4], const f16x2 (&dgl)[4],
    const char* gth, int base2, int sigh, f32x16& acc)
{
  (do_step<Ss>(kh, xh, xl, su_h, su_l, dgh, dgl, gth, base2, sigh, acc), ...);
}

// ---------------- density kernel: no LDS, theta from global (L1) ----------------
// Round-14 counters: staging writes = the bank conflicts; barriers+staging
// ~1.5-2us of the 9.8us body. Theta image (22.5KB) fits L1 (32KB/CU) ->
// read it directly; no __shared__, no __syncthreads, VGPR-only occupancy.
__global__ __launch_bounds__(256) void gm_mfma_kernel(
    const float* __restrict__ x,
    const char*  __restrict__ thimg,
    float* __restrict__ out)
{
  const int tid = threadIdx.x;
  const int lane = tid & 63;
  const int p = lane & 31;
  const int kh = lane >> 5;
  const int t = blockIdx.x * 4 + (tid >> 6);   // 1 tile per wave

  const float4* xp = (const float4*)(x + ((size_t)t * 32 + p) * D);
  float4 xv0 = xp[0], xv1 = xp[1], xv2 = xp[2], xv3 = xp[3];

  const int sig = (p & 7) ^ (p >> 3);
  const int base2 = p * LROW + ((kh ^ (sig & 1)) << 4);
  const int sigh = sig >> 1;

  float xs[16];
  xs[0]=xv0.x; xs[1]=xv0.y; xs[2]=xv0.z; xs[3]=xv0.w;
  xs[4]=xv1.x; xs[5]=xv1.y; xs[6]=xv1.z; xs[7]=xv1.w;
  xs[8]=xv2.x; xs[9]=xv2.y; xs[10]=xv2.z; xs[11]=xv2.w;
  xs[12]=xv3.x; xs[13]=xv3.y; xs[14]=xv3.z; xs[15]=xv3.w;

  // fp16 hi/lo split of x (RTZ; residual representable exactly)
  f16x2 xh[8], xl[8];
  #pragma unroll
  for (int i = 0; i < 8; ++i) {
    f16x2 h = pkrtz(xs[2*i], xs[2*i+1]);
    xh[i] = h;
    xl[i] = pkrtz(xs[2*i] - (float)h[0], xs[2*i+1] - (float)h[1]);
  }
  // pre-selected ROW u-splats: kh0 -> even x-index, kh1 -> odd (by table)
  f16x2 su_h[8], su_l[8];
  #pragma unroll
  for (int i = 0; i < 8; ++i) {
    f16x2 lo_h = __builtin_shufflevector(xh[i], xh[i], 0, 0);
    f16x2 hi_h = __builtin_shufflevector(xh[i], xh[i], 1, 1);
    su_h[i] = fint(kh ? bcst(hi_h) : bcst(lo_h));
    f16x2 lo_l = __builtin_shufflevector(xl[i], xl[i], 0, 0);
    f16x2 hi_l = __builtin_shufflevector(xl[i], xl[i], 1, 1);
    su_l[i] = fint(kh ? bcst(hi_l) : bcst(lo_l));
  }
  // odd-diagonal marshals
  f16x2 dgh[4], dgl[4];
  #pragma unroll
  for (int s = 0; s < 4; ++s) {
    dgh[s] = __builtin_shufflevector(xh[2*s], xh[2*s+1], 1, 3);
    dgl[s] = __builtin_shufflevector(xl[2*s], xl[2*s+1], 1, 3);
  }

  f32x16 acc;
  #pragma unroll
  for (int i = 0; i < 16; ++i) acc[i] = 0.f;

  all_steps(std::make_integer_sequence<int, NSTEPS>{}, kh, xh, xl,
            su_h, su_l, dgh, dgl, thimg, base2, sigh, acc);

  // lc already folded into acc via the LCSLOT pad column
  float e[16];
  #pragma unroll
  for (int i = 0; i < 16; ++i)
    e[i] = __builtin_amdgcn_exp2f(acc[i]);
  float a0 = (e[0] + e[1]) + (e[2] + e[3]);
  float a1 = (e[4] + e[5]) + (e[6] + e[7]);
  float a2 = (e[8] + e[9]) + (e[10] + e[11]);
  float a3 = (e[12] + e[13]) + (e[14] + e[15]);
  float ss = (a0 + a1) + (a2 + a3);
  ss += __shfl_xor(ss, 32);
  if (lane < 32) out[(size_t)t * 32 + p] = ss;
}

extern "C" void kernel_launch(void* const* d_in, const int* in_sizes, int n_in,
                              void* d_out, int out_size, void* d_ws, size_t ws_size,
                              hipStream_t stream) {
  const float* x        = (const float*)d_in[0];
  const float* m_w      = (const float*)d_in[1];
  const float* l_fac    = (const float*)d_in[2];
  const float* p_logits = (const float*)d_in[3];
  float* out = (float*)d_out;

  char* thimg = (char*)d_ws;   // IMG_BYTES swizzled theta image (incl. lc slot)

  gm_prep_kernel<<<K, 256, 0, stream>>>(m_w, l_fac, p_logits, thimg);
  gm_mfma_kernel<<<NBLK, 256, 0, stream>>>(x, thimg, out);
}

// Round 17
// 19.760 us; speedup vs baseline: 4.9252x; 1.1189x over previous
//
#include <hip/hip_runtime.h>
#include <math.h>
#include <utility>

#define NPTS 262144
#define K 32
#define D 16
#define R 160            // 136 triangle + 16 linear + 8 pad -> 10 MFMA K-steps
#define NSTEPS 10
#define NBLK 1024        // 4 waves/block, 2 tiles/wave -> 8192 tiles
#define LROW 352         // 20 data granules + 2 pad granules per theta row
#define IMG_BYTES 11264  // 32 rows * 352 B, SINGLE fp16 image (theta_lo dropped)
#define LCSLOT 148       // pad slot: lc_hi; slot 149 carries lc_lo; phi == 1.0

typedef _Float16 f16x2 __attribute__((ext_vector_type(2)));
typedef _Float16 f16x8 __attribute__((ext_vector_type(8)));
typedef __attribute__((ext_vector_type(16))) float f32x16;
typedef __attribute__((ext_vector_type(4))) int int4v;

// ---- compile-time dual-cell table (round-12 pairing) -------------------
struct PTab {
  short dty[40], cu0[40], cv0[40], cu1[40], cv1[40];
  short pd[160], pf[160];
  constexpr PTab() : dty{}, cu0{}, cv0{}, cu1{}, cv1{}, pd{}, pf{} {
    int n = 0;
    for (int j = 0; j < 8; ++j)                     // 28 ROW duals
      for (int i = 0; i < j; ++i) {
        dty[n]=0; cu0[n]=(short)(2*i); cv0[n]=(short)j;
        cu1[n]=(short)(2*i+1); cv1[n]=(short)j; ++n;
      }
    for (int t = 0; t < 4; ++t) {                   // 4 ROWX duals
      dty[n]=1; cu0[n]=(short)(4*t); cv0[n]=(short)(2*t);
      cu1[n]=(short)(4*t+2); cv1[n]=(short)(2*t+1); ++n;
    }
    for (int t = 0; t < 2; ++t) {                   // 2 DIAG duals
      dty[n]=2; cu0[n]=(short)(2*t); cu1[n]=(short)(2*t+1);
      cv0[n]=0; cv1[n]=0; ++n;
    }
    for (int t = 0; t < 4; ++t) {                   // 4 LIN duals
      dty[n]=3; cu0[n]=(short)(2*t); cu1[n]=(short)(2*t+1);
      cv0[n]=0; cv1[n]=0; ++n;
    }
    for (int t = 0; t < 2; ++t) {                   // 2 PAD duals (cells 38,39)
      dty[n]=4; cu0[n]=0; cu1[n]=0; cv0[n]=0; cv1[n]=0; ++n;
    }
    for (int c = 0; c < 40; ++c) {
      int S = c / 4, a = c % 4;
      for (int kh = 0; kh < 2; ++kh)
        for (int e = 0; e < 2; ++e) {
          int q = S*16 + kh*8 + a*2 + e;
          int ty = dty[c];
          int u = kh ? cu1[c] : cu0[c];
          int v = kh ? cv1[c] : cv0[c];
          if (ty == 0 || ty == 1) { pd[q] = (short)u; pf[q] = (short)(2*v + e); }
          else if (ty == 2) { int s = u; pd[q] = pf[q] = (short)(4*s + 1 + 2*e); }
          else if (ty == 3) { pd[q] = 16; pf[q] = (short)(2*u + e); }
          else { pd[q] = 17; pf[q] = 0; }
        }
    }
  }
};
static constexpr PTab TAB{};

// ---------------- prep kernel: one block per component k ----------------
// Writes a SINGLE pre-swizzled fp16 theta image. lc carried exactly via two
// pad slots: 148 = fp16(lc), 149 = fp16(lc - fp16(lc)); density phi there
// is 1.0 so the MFMA k-sum adds lc_hi + lc_lo (full precision, zero ops).
__global__ __launch_bounds__(256) void gm_prep_kernel(
    const float* __restrict__ m_w,
    const float* __restrict__ l_fac,
    const float* __restrict__ p_logits,
    char* __restrict__ thimg)
{
  const int k = blockIdx.x;
  const int tid = threadIdx.x;
  const int r = tid >> 4, c = tid & 15;
  __shared__ float A[D][D];
  __shared__ float L[D][D];
  __shared__ float S[2][D][D];
  __shared__ float Gd[D];
  __shared__ float piv[D];
  __shared__ float ld[D];
  __shared__ float sm[K];
  __shared__ float sme[K];
  __shared__ float smax;
  __shared__ float lc_sh;
  const float LOG2E = 1.4426950408889634f;

  A[r][c] = l_fac[k * D * D + r * D + c];
  if (tid < K) sm[tid] = p_logits[tid];
  __syncthreads();

  {
    float s = 0.f;
    #pragma unroll
    for (int e = 0; e < D; ++e) s += A[r][e] * A[c][e];
    s *= (1.0f / D);
    L[r][c] = s;
    S[0][r][c] = s;
  }
  if (tid == 0) {
    float mx = -1e30f;
    for (int i = 0; i < K; ++i) mx = fmaxf(mx, sm[i]);
    smax = mx;
  }
  __syncthreads();

  if (tid < D) {
    float s = 0.f;
    #pragma unroll
    for (int f = 0; f < D; ++f) s += L[tid][f] * m_w[k * D + f];
    Gd[tid] = s;
  }

  int cb = 0;
  for (int j = 0; j < 15; ++j) {
    float pj = S[cb][j][j];
    float a = S[cb][r][j], b = S[cb][c][j], v = S[cb][r][c];
    if (tid == 0) piv[j] = pj;
    if (r > j && c > j) S[cb ^ 1][r][c] = v - a * b / pj;
    cb ^= 1;
    __syncthreads();
  }
  if (tid == 0) piv[15] = S[cb][15][15];
  __syncthreads();

  // parallel transcendentals
  if (tid < D) ld[tid] = logf(piv[tid]);
  else if (tid >= 32 && tid < 32 + K) sme[tid - 32] = expf(sm[tid - 32] - smax);
  __syncthreads();

  if (tid == 0) {
    float z = 0.f;
    for (int i = 0; i < K; ++i) z += sme[i];
    float logp = sm[k] - smax - logf(z);
    float logdet_sqrt = 0.f;
    for (int j = 0; j < D; ++j) logdet_sqrt += ld[j];
    logdet_sqrt *= 0.5f;
    float cc = 0.f;
    for (int d2 = 0; d2 < D; ++d2) cc += m_w[k * D + d2] * Gd[d2];
    float lc = logp - 14.703016531274763f + logdet_sqrt - 0.5f * cc;
    lc_sh = LOG2E * lc;
  }
  __syncthreads();

  // theta -> fp16 (RNE), pre-swizzled single image; lc hi/lo at 148/149
  for (int q = tid; q < R; q += 256) {
    int d = TAB.pd[q], f = TAB.pf[q];
    float th;
    if (q == LCSLOT) th = lc_sh;
    else if (q == LCSLOT + 1) th = lc_sh - (float)((_Float16)lc_sh);
    else if (d == 17) th = 0.f;
    else if (d == 16) th = LOG2E * Gd[f];
    else th = ((d == f) ? -0.5f : -1.0f) * LOG2E * L[d][f];
    _Float16 h = (_Float16)th;           // RNE
    int m = q >> 3, e = q & 7;
    int sg = (k & 7) ^ (k >> 3);
    int phys = (m < 16) ? (m ^ sg) : (16 + ((m - 16) ^ (sg & 3)));
    size_t off = (size_t)k * LROW + (size_t)phys * 16 + (size_t)e * 2;
    *(unsigned short*)(thimg + off) = __builtin_bit_cast(unsigned short, h);
  }
}

__device__ __forceinline__ int bcst(f16x2 v) { return __builtin_bit_cast(int, v); }
__device__ __forceinline__ f16x2 fint(int v) { return __builtin_bit_cast(f16x2, v); }
__device__ __forceinline__ f16x2 pkrtz(float a, float b) {
  return __builtin_bit_cast(f16x2, __builtin_amdgcn_cvt_pkrtz(a, b));
}

// build one dword of (phi_hh, phi_cross) for dual C
template<int C>
__device__ __forceinline__ void dualphi(int kh,
    const f16x2 (&xh)[8], const f16x2 (&xl)[8],
    const f16x2 (&su_h)[8], const f16x2 (&su_l)[8],
    const f16x2 (&dgh)[4], const f16x2 (&dgl)[4],
    int& hh, int& cx)
{
  constexpr int ty = TAB.dty[C];
  constexpr int U0 = TAB.cu0[C], V0 = TAB.cv0[C];
  constexpr int U1 = TAB.cu1[C], V1 = TAB.cv1[C];
  if constexpr (ty == 4) {
    if constexpr (C == 38) { hh = 0x3C003C00; cx = 0; }  // (1.0,1.0): lc hi+lo
    else { hh = 0; cx = 0; }
  } else if constexpr (ty == 3) {                 // linear: phi = x
    hh = kh ? bcst(xh[U1]) : bcst(xh[U0]);
    cx = kh ? bcst(xl[U1]) : bcst(xl[U0]);
  } else if constexpr (ty == 2) {                 // odd diagonals: x_d^2
    f16x2 Dh = fint(kh ? bcst(dgh[U1]) : bcst(dgh[U0]));
    f16x2 Dl = fint(kh ? bcst(dgl[U1]) : bcst(dgl[U0]));
    f16x2 m = Dh * Dl;
    hh = bcst(Dh * Dh);
    cx = bcst(m + m);
  } else if constexpr (ty == 1) {                 // ROWX: even-diag leftovers
    constexpr int T = U0 >> 2;
    f16x2 uh = fint(kh ? bcst(xh[2*T+1]) : bcst(xh[2*T]));
    f16x2 ul = fint(kh ? bcst(xl[2*T+1]) : bcst(xl[2*T]));
    f16x2 Uh = __builtin_shufflevector(uh, uh, 0, 0);
    f16x2 Ul = __builtin_shufflevector(ul, ul, 0, 0);
    f16x2 Vh = fint(kh ? bcst(xh[V1]) : bcst(xh[V0]));
    f16x2 Vl = fint(kh ? bcst(xl[V1]) : bcst(xl[V0]));
    hh = bcst(Uh * Vh);
    cx = bcst(__builtin_elementwise_fma(Uh, Vl, Ul * Vh));
  } else {                                        // ROW: pre-selected splat
    constexpr int I = U0 >> 1;
    f16x2 Uh = su_h[I], Ul = su_l[I];
    f16x2 Vh = xh[V0], Vl = xl[V0];               // V0==V1 for ROW
    hh = bcst(Uh * Vh);
    cx = bcst(__builtin_elementwise_fma(Uh, Vl, Ul * Vh));
  }
}

// 2 MFMA per step: theta x phi_hh and theta x phi_cross (theta_lo dropped;
// error budget: +~1-2e-13 absmax, threshold 8.4e-13)
template<int S>
__device__ __forceinline__ void do_step(int kh,
    const f16x2 (&xh)[8], const f16x2 (&xl)[8],
    const f16x2 (&su_h)[8], const f16x2 (&su_l)[8],
    const f16x2 (&dgh)[4], const f16x2 (&dgl)[4],
    const char* lthp, int base2, int sigh, f32x16& acc)
{
  int va;
  if constexpr (S < 8) va = base2 + ((S ^ sigh) << 5);
  else                 va = base2 + 256 + (((S - 8) ^ (sigh & 1)) << 5);
  int4v thv = *(const int4v*)(lthp + va);
  int h0, h1, h2, h3, c0, c1, c2, c3;
  dualphi<S*4+0>(kh, xh, xl, su_h, su_l, dgh, dgl, h0, c0);
  dualphi<S*4+1>(kh, xh, xl, su_h, su_l, dgh, dgl, h1, c1);
  dualphi<S*4+2>(kh, xh, xl, su_h, su_l, dgh, dgl, h2, c2);
  dualphi<S*4+3>(kh, xh, xl, su_h, su_l, dgh, dgl, h3, c3);
  int4v hh = {h0, h1, h2, h3};
  int4v cx = {c0, c1, c2, c3};
  acc = __builtin_amdgcn_mfma_f32_32x32x16_f16(
      __builtin_bit_cast(f16x8, thv), __builtin_bit_cast(f16x8, hh), acc, 0, 0, 0);
  acc = __builtin_amdgcn_mfma_f32_32x32x16_f16(
      __builtin_bit_cast(f16x8, thv), __builtin_bit_cast(f16x8, cx), acc, 0, 0, 0);
}

template<int... Ss>
__device__ __forceinline__ void all_steps(std::integer_sequence<int, Ss...>,
    int kh, const f16x2 (&xh)[8], const f16x2 (&xl)[8],
    const f16x2 (&su_h)[8], const f16x2 (&su_l)[8],
    const f16x2 (&dgh)[4], const f16x2 (&dgl)[4],
    const char* lthp, int base2, int sigh, f32x16& acc)
{
  (do_step<Ss>(kh, xh, xl, su_h, su_l, dgh, dgl, lthp, base2, sigh, acc), ...);
}

// full per-tile pipeline from raw float4 x regs to the out store
__device__ __forceinline__ void process_tile(
    const float4 (&xv)[4], int t, int lane, int p, int kh,
    const char* lthp, int base2, int sigh, float* __restrict__ out)
{
  float xs[16];
  xs[0]=xv[0].x; xs[1]=xv[0].y; xs[2]=xv[0].z; xs[3]=xv[0].w;
  xs[4]=xv[1].x; xs[5]=xv[1].y; xs[6]=xv[1].z; xs[7]=xv[1].w;
  xs[8]=xv[2].x; xs[9]=xv[2].y; xs[10]=xv[2].z; xs[11]=xv[2].w;
  xs[12]=xv[3].x; xs[13]=xv[3].y; xs[14]=xv[3].z; xs[15]=xv[3].w;

  f16x2 xh[8], xl[8];
  #pragma unroll
  for (int i = 0; i < 8; ++i) {
    f16x2 h = pkrtz(xs[2*i], xs[2*i+1]);
    xh[i] = h;
    xl[i] = pkrtz(xs[2*i] - (float)h[0], xs[2*i+1] - (float)h[1]);
  }
  f16x2 su_h[8], su_l[8];
  #pragma unroll
  for (int i = 0; i < 8; ++i) {
    f16x2 lo_h = __builtin_shufflevector(xh[i], xh[i], 0, 0);
    f16x2 hi_h = __builtin_shufflevector(xh[i], xh[i], 1, 1);
    su_h[i] = fint(kh ? bcst(hi_h) : bcst(lo_h));
    f16x2 lo_l = __builtin_shufflevector(xl[i], xl[i], 0, 0);
    f16x2 hi_l = __builtin_shufflevector(xl[i], xl[i], 1, 1);
    su_l[i] = fint(kh ? bcst(hi_l) : bcst(lo_l));
  }
  f16x2 dgh[4], dgl[4];
  #pragma unroll
  for (int s = 0; s < 4; ++s) {
    dgh[s] = __builtin_shufflevector(xh[2*s], xh[2*s+1], 1, 3);
    dgl[s] = __builtin_shufflevector(xl[2*s], xl[2*s+1], 1, 3);
  }

  f32x16 acc;
  #pragma unroll
  for (int i = 0; i < 16; ++i) acc[i] = 0.f;

  all_steps(std::make_integer_sequence<int, NSTEPS>{}, kh, xh, xl,
            su_h, su_l, dgh, dgl, lthp, base2, sigh, acc);

  float e[16];
  #pragma unroll
  for (int i = 0; i < 16; ++i)
    e[i] = __builtin_amdgcn_exp2f(acc[i]);     // lc folded via slots 148/149
  float a0 = (e[0] + e[1]) + (e[2] + e[3]);
  float a1 = (e[4] + e[5]) + (e[6] + e[7]);
  float a2 = (e[8] + e[9]) + (e[10] + e[11]);
  float a3 = (e[12] + e[13]) + (e[14] + e[15]);
  float ss = (a0 + a1) + (a2 + a3);
  ss += __shfl_xor(ss, 32);
  if (lane < 32) out[(size_t)t * 32 + p] = ss;
}

// ---------------- density kernel: 2 tiles/wave, single theta image ----------------
// r13 shell (best: 21.3us) + halved image (theta_lo dropped -> 11.3KB stage,
// 10 ds_read_b128/tile, 20 MFMA/tile) + lc folded into pad slots.
__global__ __launch_bounds__(256) void gm_mfma_kernel(
    const float* __restrict__ x,
    const char*  __restrict__ thimg,
    float* __restrict__ out)
{
  __shared__ __align__(16) char lth[IMG_BYTES];
  const int tid = threadIdx.x;
  const int lane = tid & 63;
  const int p = lane & 31;
  const int kh = lane >> 5;
  const int t0 = (blockIdx.x * 4 + (tid >> 6)) * 2;   // 2 tiles per wave

  // issue both tiles' x loads first (latency hides under staging+barrier)
  const float4* xp0 = (const float4*)(x + ((size_t)t0 * 32 + p) * D);
  const float4* xp1 = (const float4*)(x + ((size_t)(t0 + 1) * 32 + p) * D);
  float4 xva[4], xvb[4];
  #pragma unroll
  for (int i = 0; i < 4; ++i) { xva[i] = xp0[i]; xvb[i] = xp1[i]; }

  // stage theta image -> LDS, pure linear copy (pre-swizzled by prep)
  for (int i = tid; i < IMG_BYTES / 16; i += 256) {
    int4v v = *(const int4v*)(thimg + i * 16);
    *(int4v*)(lth + i * 16) = v;
  }
  __syncthreads();

  const int sig = (p & 7) ^ (p >> 3);
  const int base2 = p * LROW + ((kh ^ (sig & 1)) << 4);
  const int sigh = sig >> 1;

  process_tile(xva, t0,     lane, p, kh, lth, base2, sigh, out);
  process_tile(xvb, t0 + 1, lane, p, kh, lth, base2, sigh, out);
}

extern "C" void kernel_launch(void* const* d_in, const int* in_sizes, int n_in,
                              void* d_out, int out_size, void* d_ws, size_t ws_size,
                              hipStream_t stream) {
  const float* x        = (const float*)d_in[0];
  const float* m_w      = (const float*)d_in[1];
  const float* l_fac    = (const float*)d_in[2];
  const float* p_logits = (const float*)d_in[3];
  float* out = (float*)d_out;
  char* thimg = (char*)d_ws;   // IMG_BYTES pre-swizzled fp16 theta image

  gm_prep_kernel<<<K, 256, 0, stream>>>(m_w, l_fac, p_logits, thimg);
  gm_mfma_kernel<<<NBLK, 256, 0, stream>>>(x, thimg, out);
}

// Round 18
// 16.958 us; speedup vs baseline: 5.7390x; 1.1652x over previous
//
#include <hip/hip_runtime.h>
#include <math.h>
#include <utility>

#define NPTS 262144
#define K 32
#define D 16
#define R 160            // 136 triangle + 16 linear + 8 pad -> 10 MFMA K-steps
#define NSTEPS 10
#define NBLK 1024        // 4 waves/block, 2 tiles/wave -> 8192 tiles
#define LROW 352         // 20 data granules + 2 pad granules per theta row
#define IMG_BYTES 11264  // 32 rows * 352 B, single fp16 theta image
#define LCSLOT 148       // pad slot: lc_hi; slot 149: lc_lo; phi there == 1.0

typedef _Float16 f16x2 __attribute__((ext_vector_type(2)));
typedef _Float16 f16x8 __attribute__((ext_vector_type(8)));
typedef __attribute__((ext_vector_type(16))) float f32x16;
typedef __attribute__((ext_vector_type(4))) int int4v;

// ---- compile-time dual-cell table (round-12 pairing) -------------------
struct PTab {
  short dty[40], cu0[40], cv0[40], cu1[40], cv1[40];
  short pd[160], pf[160];
  constexpr PTab() : dty{}, cu0{}, cv0{}, cu1{}, cv1{}, pd{}, pf{} {
    int n = 0;
    for (int j = 0; j < 8; ++j)                     // 28 ROW duals
      for (int i = 0; i < j; ++i) {
        dty[n]=0; cu0[n]=(short)(2*i); cv0[n]=(short)j;
        cu1[n]=(short)(2*i+1); cv1[n]=(short)j; ++n;
      }
    for (int t = 0; t < 4; ++t) {                   // 4 ROWX duals
      dty[n]=1; cu0[n]=(short)(4*t); cv0[n]=(short)(2*t);
      cu1[n]=(short)(4*t+2); cv1[n]=(short)(2*t+1); ++n;
    }
    for (int t = 0; t < 2; ++t) {                   // 2 DIAG duals
      dty[n]=2; cu0[n]=(short)(2*t); cu1[n]=(short)(2*t+1);
      cv0[n]=0; cv1[n]=0; ++n;
    }
    for (int t = 0; t < 4; ++t) {                   // 4 LIN duals
      dty[n]=3; cu0[n]=(short)(2*t); cu1[n]=(short)(2*t+1);
      cv0[n]=0; cv1[n]=0; ++n;
    }
    for (int t = 0; t < 2; ++t) {                   // 2 PAD duals (cells 38,39)
      dty[n]=4; cu0[n]=0; cu1[n]=0; cv0[n]=0; cv1[n]=0; ++n;
    }
    for (int c = 0; c < 40; ++c) {
      int S = c / 4, a = c % 4;
      for (int kh = 0; kh < 2; ++kh)
        for (int e = 0; e < 2; ++e) {
          int q = S*16 + kh*8 + a*2 + e;
          int ty = dty[c];
          int u = kh ? cu1[c] : cu0[c];
          int v = kh ? cv1[c] : cv0[c];
          if (ty == 0 || ty == 1) { pd[q] = (short)u; pf[q] = (short)(2*v + e); }
          else if (ty == 2) { int s = u; pd[q] = pf[q] = (short)(4*s + 1 + 2*e); }
          else if (ty == 3) { pd[q] = 16; pf[q] = (short)(2*u + e); }
          else { pd[q] = 17; pf[q] = 0; }
        }
    }
  }
};
static constexpr PTab TAB{};

// ---------------- prep kernel: one block per component k ----------------
// Single pre-swizzled fp16 (RNE) theta image; lc carried exactly via pad
// slots 148 (hi) and 149 (lo residual), phi there == 1.0.
__global__ __launch_bounds__(256) void gm_prep_kernel(
    const float* __restrict__ m_w,
    const float* __restrict__ l_fac,
    const float* __restrict__ p_logits,
    char* __restrict__ thimg)
{
  const int k = blockIdx.x;
  const int tid = threadIdx.x;
  const int r = tid >> 4, c = tid & 15;
  __shared__ float A[D][D];
  __shared__ float L[D][D];
  __shared__ float S[2][D][D];
  __shared__ float Gd[D];
  __shared__ float piv[D];
  __shared__ float ld[D];
  __shared__ float sm[K];
  __shared__ float sme[K];
  __shared__ float smax;
  __shared__ float lc_sh;
  const float LOG2E = 1.4426950408889634f;

  A[r][c] = l_fac[k * D * D + r * D + c];
  if (tid < K) sm[tid] = p_logits[tid];
  __syncthreads();

  {
    float s = 0.f;
    #pragma unroll
    for (int e = 0; e < D; ++e) s += A[r][e] * A[c][e];
    s *= (1.0f / D);
    L[r][c] = s;
    S[0][r][c] = s;
  }
  if (tid == 0) {
    float mx = -1e30f;
    for (int i = 0; i < K; ++i) mx = fmaxf(mx, sm[i]);
    smax = mx;
  }
  __syncthreads();

  if (tid < D) {
    float s = 0.f;
    #pragma unroll
    for (int f = 0; f < D; ++f) s += L[tid][f] * m_w[k * D + f];
    Gd[tid] = s;
  }

  int cb = 0;
  for (int j = 0; j < 15; ++j) {
    float pj = S[cb][j][j];
    float a = S[cb][r][j], b = S[cb][c][j], v = S[cb][r][c];
    if (tid == 0) piv[j] = pj;
    if (r > j && c > j) S[cb ^ 1][r][c] = v - a * b / pj;
    cb ^= 1;
    __syncthreads();
  }
  if (tid == 0) piv[15] = S[cb][15][15];
  __syncthreads();

  // parallel transcendentals
  if (tid < D) ld[tid] = logf(piv[tid]);
  else if (tid >= 32 && tid < 32 + K) sme[tid - 32] = expf(sm[tid - 32] - smax);
  __syncthreads();

  if (tid == 0) {
    float z = 0.f;
    for (int i = 0; i < K; ++i) z += sme[i];
    float logp = sm[k] - smax - logf(z);
    float logdet_sqrt = 0.f;
    for (int j = 0; j < D; ++j) logdet_sqrt += ld[j];
    logdet_sqrt *= 0.5f;
    float cc = 0.f;
    for (int d2 = 0; d2 < D; ++d2) cc += m_w[k * D + d2] * Gd[d2];
    float lc = logp - 14.703016531274763f + logdet_sqrt - 0.5f * cc;
    lc_sh = LOG2E * lc;
  }
  __syncthreads();

  // theta -> fp16 (RNE), pre-swizzled single image; lc hi/lo at 148/149
  for (int q = tid; q < R; q += 256) {
    int d = TAB.pd[q], f = TAB.pf[q];
    float th;
    if (q == LCSLOT) th = lc_sh;
    else if (q == LCSLOT + 1) th = lc_sh - (float)((_Float16)lc_sh);
    else if (d == 17) th = 0.f;
    else if (d == 16) th = LOG2E * Gd[f];
    else th = ((d == f) ? -0.5f : -1.0f) * LOG2E * L[d][f];
    _Float16 h = (_Float16)th;           // RNE
    int m = q >> 3, e = q & 7;
    int sg = (k & 7) ^ (k >> 3);
    int phys = (m < 16) ? (m ^ sg) : (16 + ((m - 16) ^ (sg & 3)));
    size_t off = (size_t)k * LROW + (size_t)phys * 16 + (size_t)e * 2;
    *(unsigned short*)(thimg + off) = __builtin_bit_cast(unsigned short, h);
  }
}

__device__ __forceinline__ int bcst(f16x2 v) { return __builtin_bit_cast(int, v); }
__device__ __forceinline__ f16x2 fint(int v) { return __builtin_bit_cast(f16x2, v); }

// one fp16x2 phi dword for dual C (hi-only; cross term dropped)
template<int C>
__device__ __forceinline__ int dualphi_h(int kh,
    const f16x2 (&xh)[8], const f16x2 (&su_h)[8], const f16x2 (&dgh)[4])
{
  constexpr int ty = TAB.dty[C];
  constexpr int U0 = TAB.cu0[C], V0 = TAB.cv0[C];
  constexpr int U1 = TAB.cu1[C], V1 = TAB.cv1[C];
  if constexpr (ty == 4) {
    if constexpr (C == 38) return 0x3C003C00;    // (1.0,1.0): lc hi+lo slots
    else return 0;
  } else if constexpr (ty == 3) {                 // linear: phi = x
    return kh ? bcst(xh[U1]) : bcst(xh[U0]);
  } else if constexpr (ty == 2) {                 // odd diagonals: x_d^2
    f16x2 Dh = fint(kh ? bcst(dgh[U1]) : bcst(dgh[U0]));
    return bcst(Dh * Dh);
  } else if constexpr (ty == 1) {                 // ROWX: even-diag leftovers
    constexpr int T = U0 >> 2;
    f16x2 uh = fint(kh ? bcst(xh[2*T+1]) : bcst(xh[2*T]));
    f16x2 Uh = __builtin_shufflevector(uh, uh, 0, 0);
    f16x2 Vh = fint(kh ? bcst(xh[V1]) : bcst(xh[V0]));
    return bcst(Uh * Vh);
  } else {                                        // ROW: pre-selected splat
    constexpr int I = U0 >> 1;
    return bcst(su_h[I] * xh[V0]);                // V0==V1 for ROW
  }
}

// 1 MFMA per step (10 per tile)
template<int S>
__device__ __forceinline__ void do_step(int kh,
    const f16x2 (&xh)[8], const f16x2 (&su_h)[8], const f16x2 (&dgh)[4],
    const char* lthp, int base2, int sigh, f32x16& acc)
{
  int va;
  if constexpr (S < 8) va = base2 + ((S ^ sigh) << 5);
  else                 va = base2 + 256 + (((S - 8) ^ (sigh & 1)) << 5);
  int4v thv = *(const int4v*)(lthp + va);
  int4v hh = { dualphi_h<S*4+0>(kh, xh, su_h, dgh),
               dualphi_h<S*4+1>(kh, xh, su_h, dgh),
               dualphi_h<S*4+2>(kh, xh, su_h, dgh),
               dualphi_h<S*4+3>(kh, xh, su_h, dgh) };
  acc = __builtin_amdgcn_mfma_f32_32x32x16_f16(
      __builtin_bit_cast(f16x8, thv), __builtin_bit_cast(f16x8, hh), acc, 0, 0, 0);
}

template<int... Ss>
__device__ __forceinline__ void all_steps(std::integer_sequence<int, Ss...>,
    int kh, const f16x2 (&xh)[8], const f16x2 (&su_h)[8], const f16x2 (&dgh)[4],
    const char* lthp, int base2, int sigh, f32x16& acc)
{
  (do_step<Ss>(kh, xh, su_h, dgh, lthp, base2, sigh, acc), ...);
}

// per-tile pipeline; x -> fp16 via RNE (scalar cvt) since no lo-correction
__device__ __forceinline__ void process_tile(
    const float4 (&xv)[4], int t, int lane, int p, int kh,
    const char* lthp, int base2, int sigh, float* __restrict__ out)
{
  float xs[16];
  xs[0]=xv[0].x; xs[1]=xv[0].y; xs[2]=xv[0].z; xs[3]=xv[0].w;
  xs[4]=xv[1].x; xs[5]=xv[1].y; xs[6]=xv[1].z; xs[7]=xv[1].w;
  xs[8]=xv[2].x; xs[9]=xv[2].y; xs[10]=xv[2].z; xs[11]=xv[2].w;
  xs[12]=xv[3].x; xs[13]=xv[3].y; xs[14]=xv[3].z; xs[15]=xv[3].w;

  f16x2 xh[8];
  #pragma unroll
  for (int i = 0; i < 8; ++i)
    xh[i] = f16x2{(_Float16)xs[2*i], (_Float16)xs[2*i+1]};   // RNE

  f16x2 su_h[8];
  #pragma unroll
  for (int i = 0; i < 8; ++i) {
    f16x2 lo = __builtin_shufflevector(xh[i], xh[i], 0, 0);
    f16x2 hi = __builtin_shufflevector(xh[i], xh[i], 1, 1);
    su_h[i] = fint(kh ? bcst(hi) : bcst(lo));
  }
  f16x2 dgh[4];
  #pragma unroll
  for (int s = 0; s < 4; ++s)
    dgh[s] = __builtin_shufflevector(xh[2*s], xh[2*s+1], 1, 3);

  f32x16 acc;
  #pragma unroll
  for (int i = 0; i < 16; ++i) acc[i] = 0.f;

  all_steps(std::make_integer_sequence<int, NSTEPS>{}, kh, xh, su_h, dgh,
            lthp, base2, sigh, acc);

  float e[16];
  #pragma unroll
  for (int i = 0; i < 16; ++i)
    e[i] = __builtin_amdgcn_exp2f(acc[i]);     // lc folded via slots 148/149
  float a0 = (e[0] + e[1]) + (e[2] + e[3]);
  float a1 = (e[4] + e[5]) + (e[6] + e[7]);
  float a2 = (e[8] + e[9]) + (e[10] + e[11]);
  float a3 = (e[12] + e[13]) + (e[14] + e[15]);
  float ss = (a0 + a1) + (a2 + a3);
  ss += __shfl_xor(ss, 32);
  if (lane < 32) out[(size_t)t * 32 + p] = ss;
}

// ---------------- density kernel: 2 tiles/wave via unroll-1 loop ----------------
// Code size halved (one emitted copy of the 10-step body) to cut cold-I$
// first-pass cost; register rotation keeps all x indices compile-time
// (rule #20: no runtime-indexed arrays).
__global__ __launch_bounds__(256) void gm_mfma_kernel(
    const float* __restrict__ x,
    const char*  __restrict__ thimg,
    float* __restrict__ out)
{
  __shared__ __align__(16) char lth[IMG_BYTES];
  const int tid = threadIdx.x;
  const int lane = tid & 63;
  const int p = lane & 31;
  const int kh = lane >> 5;
  const int t0 = (blockIdx.x * 4 + (tid >> 6)) * 2;   // 2 tiles per wave

  // issue both tiles' x loads first (latency hides under staging+barrier)
  const float4* xp0 = (const float4*)(x + ((size_t)t0 * 32 + p) * D);
  const float4* xp1 = (const float4*)(x + ((size_t)(t0 + 1) * 32 + p) * D);
  float4 cur[4], nxt[4];
  #pragma unroll
  for (int i = 0; i < 4; ++i) { cur[i] = xp0[i]; nxt[i] = xp1[i]; }

  // stage theta image -> LDS, pure linear copy (pre-swizzled by prep)
  for (int i = tid; i < IMG_BYTES / 16; i += 256) {
    int4v v = *(const int4v*)(thimg + i * 16);
    *(int4v*)(lth + i * 16) = v;
  }
  __syncthreads();

  const int sig = (p & 7) ^ (p >> 3);
  const int base2 = p * LROW + ((kh ^ (sig & 1)) << 4);
  const int sigh = sig >> 1;

  #pragma unroll 1
  for (int tt = 0; tt < 2; ++tt) {
    process_tile(cur, t0 + tt, lane, p, kh, lth, base2, sigh, out);
    #pragma unroll
    for (int i = 0; i < 4; ++i) cur[i] = nxt[i];   // static-index rotation
  }
}

extern "C" void kernel_launch(void* const* d_in, const int* in_sizes, int n_in,
                              void* d_out, int out_size, void* d_ws, size_t ws_size,
                              hipStream_t stream) {
  const float* x        = (const float*)d_in[0];
  const float* m_w      = (const float*)d_in[1];
  const float* l_fac    = (const float*)d_in[2];
  const float* p_logits = (const float*)d_in[3];
  float* out = (float*)d_out;
  char* thimg = (char*)d_ws;   // IMG_BYTES pre-swizzled fp16 theta image

  gm_prep_kernel<<<K, 256, 0, stream>>>(m_w, l_fac, p_logits, thimg);
  gm_mfma_kernel<<<NBLK, 256, 0, stream>>>(x, thimg, out);
}